// Round 7
// baseline (409.057 us; speedup 1.0000x reference)
//
#include <hip/hip_runtime.h>

// LinearAttention forward. B=2, T=8192 (BT=16384), HID=1024, H=8, DK=DV=128.
// ws (MB): [0,32) Q/O | [32,64) Kf | [64,96) VT | [96,160) KV (Xb overlays) |
//   [160,168) W bf16 | [168,+128KB) fm weights bf16
// R12: GEMM core reverted to R10 (coarse ring + register prefetch, 100.4us
//   measured; R11 8-phase was 107us -- LDS-read time ~= MFMA time makes
//   per-phase lgkmcnt(0) serialization a ~50% MfmaUtil ceiling, and 96
//   barriers/loop at 1 block/CU cost more than fine interleave gained).
// R12 non-GEMM: attn loads S fragments global->register (removes 2 LDS
//   staging passes + 4 barriers); cumsum batches 8 loads in flight.

typedef __bf16 bf16x8 __attribute__((ext_vector_type(8)));
typedef float  f32x4  __attribute__((ext_vector_type(4)));

__device__ __forceinline__ float bf2f(unsigned short u) {
  union { unsigned int i; float f; } v; v.i = ((unsigned int)u) << 16; return v.f;
}
__device__ __forceinline__ unsigned short f2bf(float f) {
  union { float f; unsigned int i; } v; v.f = f;
  return (unsigned short)((v.i + 0x8000u) >> 16);
}
__device__ __forceinline__ unsigned int pk2(float a, float b) {
  union { float f; unsigned int i; } x, y; x.f = a; y.f = b;
  return ((x.i + 0x8000u) >> 16) | ((y.i + 0x8000u) & 0xFFFF0000u);
}
__device__ __forceinline__ f32x4 mfma16(bf16x8 a, bf16x8 b, f32x4 c) {
  return __builtin_amdgcn_mfma_f32_16x16x32_bf16(a, b, c, 0, 0, 0);
}
__device__ __forceinline__ void gl_lds16(const unsigned short* g, unsigned short* l) {
  __builtin_amdgcn_global_load_lds((const __attribute__((address_space(1))) void*)g,
                                   (__attribute__((address_space(3))) void*)l, 16, 0, 0);
}

__global__ void __launch_bounds__(256)
cvt_kernel(const float* __restrict__ s, unsigned short* __restrict__ d, int n4) {
  const int i = blockIdx.x * 256 + threadIdx.x;
  if (i >= n4) return;
  const float4 f = ((const float4*)s)[i];
  uint2 o; o.x = pk2(f.x, f.y); o.y = pk2(f.z, f.w);
  ((uint2*)d)[i] = o;
}
__global__ void __launch_bounds__(256)
cvt4_kernel(const float* __restrict__ s0, const float* __restrict__ s1,
            const float* __restrict__ s2, const float* __restrict__ s3,
            unsigned short* __restrict__ d0, unsigned short* __restrict__ d1,
            unsigned short* __restrict__ d2, unsigned short* __restrict__ d3,
            int n4) {
  const int w = blockIdx.y;
  const float* s = (w == 0) ? s0 : (w == 1) ? s1 : (w == 2) ? s2 : s3;
  unsigned short* d = (w == 0) ? d0 : (w == 1) ? d1 : (w == 2) ? d2 : d3;
  const int i = blockIdx.x * 256 + threadIdx.x;
  if (i >= n4) return;
  const float4 f = ((const float4*)s)[i];
  uint2 o; o.x = pk2(f.x, f.y); o.y = pk2(f.z, f.w);
  ((uint2*)d)[i] = o;
}

// slot s of a swizzled 256x32 unit: j=s>>3, c=(s&7)^(j&7), row=2j+(c>>2),
// k-chunk c&3. Returns element offset in global [256,1024] source.
__device__ __forceinline__ int stage_goff(int s) {
  const int j = s >> 3, c = (s & 7) ^ (j & 7);
  return (2 * j + (c >> 2)) * 1024 + (c & 3) * 8;
}

// R10 core: 4-deep LDS ring, one barrier per 32-K step, register-prefetch one
// subtile ahead so ds_reads of step u+1 drain during the 32-MFMA cluster of u.
__device__ __forceinline__ void gemm256_loop(const unsigned short* __restrict__ gA,
                                             const unsigned short* __restrict__ gB,
                                             unsigned short* __restrict__ ldsA,
                                             unsigned short* __restrict__ ldsB,
                                             int tid, f32x4 (&acc)[8][4]) {
  const int lane = tid & 63, wid = tid >> 6;
  const int lq = lane & 15, quad = lane >> 4;
  const int wm = (wid >> 2) * 128, wn = (wid & 3) * 64;

  const unsigned short* gA0 = gA + stage_goff(tid);
  const unsigned short* gA1 = gA + stage_goff(512 + tid);
  const unsigned short* gB0 = gB + stage_goff(tid);
  const unsigned short* gB1 = gB + stage_goff(512 + tid);
  const int l0 = wid * 512;
  const int l1 = 4096 + wid * 512;
  const int soff = (lq >> 1) * 64 + (((((lq & 1) << 2) + quad) ^ ((lq >> 1) & 7))) * 8;

#pragma unroll
  for (int h = 0; h < 3; ++h) {
    gl_lds16(gA0 + h * 32, ldsA + h * 8192 + l0);
    gl_lds16(gA1 + h * 32, ldsA + h * 8192 + l1);
    gl_lds16(gB0 + h * 32, ldsB + h * 8192 + l0);
    gl_lds16(gB1 + h * 32, ldsB + h * 8192 + l1);
  }
  asm volatile("s_waitcnt vmcnt(4)" ::: "memory");
  __builtin_amdgcn_s_barrier();
  __builtin_amdgcn_sched_barrier(0);

  bf16x8 pa[2][8], pb[2][4];
#pragma unroll
  for (int f = 0; f < 8; ++f)
    pa[0][f] = *(const bf16x8*)(ldsA + (wm + f * 16) * 32 + soff);
#pragma unroll
  for (int g = 0; g < 4; ++g)
    pb[0][g] = *(const bf16x8*)(ldsB + (wn + g * 16) * 32 + soff);

#pragma unroll
  for (int u = 0; u < 32; ++u) {
    const int cur = u & 1, nxt = cur ^ 1;
    if (u > 0) {
      if (u < 30) asm volatile("s_waitcnt vmcnt(4)" ::: "memory");
      else        asm volatile("s_waitcnt vmcnt(0)" ::: "memory");
      __builtin_amdgcn_s_barrier();
      __builtin_amdgcn_sched_barrier(0);
    }
    if (u < 29) {
      unsigned short* sa = ldsA + ((u + 3) & 3) * 8192;
      unsigned short* sb = ldsB + ((u + 3) & 3) * 8192;
      gl_lds16(gA0 + (u + 3) * 32, sa + l0);
      gl_lds16(gA1 + (u + 3) * 32, sa + l1);
      gl_lds16(gB0 + (u + 3) * 32, sb + l0);
      gl_lds16(gB1 + (u + 3) * 32, sb + l1);
    }
    if (u < 31) {
      const unsigned short* An = ldsA + ((u + 1) & 3) * 8192;
      const unsigned short* Bn = ldsB + ((u + 1) & 3) * 8192;
#pragma unroll
      for (int f = 0; f < 8; ++f)
        pa[nxt][f] = *(const bf16x8*)(An + (wm + f * 16) * 32 + soff);
#pragma unroll
      for (int g = 0; g < 4; ++g)
        pb[nxt][g] = *(const bf16x8*)(Bn + (wn + g * 16) * 32 + soff);
    }
    __builtin_amdgcn_s_setprio(1);
#pragma unroll
    for (int f = 0; f < 8; ++f)
#pragma unroll
      for (int g = 0; g < 4; ++g)
        acc[f][g] = mfma16(pa[cur][f], pb[cur][g], acc[f][g]);
    __builtin_amdgcn_s_setprio(0);
  }
}

__global__ void __launch_bounds__(512, 2)
qkv_gemm256(const unsigned short* __restrict__ Xb,
            const unsigned short* __restrict__ Wqb, const unsigned short* __restrict__ Wkb,
            const unsigned short* __restrict__ Wvb,
            unsigned short* __restrict__ Q, unsigned short* __restrict__ Kf,
            unsigned short* __restrict__ VT) {
  extern __shared__ unsigned short lds[];
  const int tid = threadIdx.x;
  const int bx = blockIdx.x;
  // XCD-local mapping: XCD (bx&7) owns 8 fixed A-tiles, sweeps 12 ct.
  const int tm = (bx & 7) * 8 + ((bx >> 3) & 7);  // 0..63
  const int ct = bx >> 6;                          // 0..11
  const int sel = ct >> 2;
  const int rowBase = tm * 256, colBase = (ct & 3) * 256;
  const unsigned short* Bw = (sel == 0) ? Wqb : ((sel == 1) ? Wkb : Wvb);

  f32x4 acc[8][4] = {};
  gemm256_loop(Xb + (size_t)rowBase * 1024, Bw + (size_t)colBase * 1024,
               lds, lds + 32768, tid, acc);

  const int lane = tid & 63, wid = tid >> 6;
  const int lq = lane & 15, quad = lane >> 4;
  const int wm = (wid >> 2) * 128, wn = (wid & 3) * 64;
  if (sel < 2) {
    unsigned short* C = (sel == 0) ? Q : Kf;
#pragma unroll
    for (int f = 0; f < 8; ++f)
#pragma unroll
      for (int g = 0; g < 4; ++g) {
        const int col = colBase + wn + g * 16 + lq;
#pragma unroll
        for (int r = 0; r < 4; ++r) {
          const int row = rowBase + wm + f * 16 + quad * 4 + r;
          C[(size_t)row * 1024 + col] = f2bf(acc[f][g][r]);
        }
      }
  } else {
#pragma unroll
    for (int f = 0; f < 8; ++f)
#pragma unroll
      for (int g = 0; g < 4; ++g) {
        const int col = colBase + wn + g * 16 + lq;
        const int h = col >> 7, dv = col & 127;
        const int row0 = rowBase + wm + f * 16 + quad * 4;
        const int b = row0 >> 13, tl = row0 & 8191;
        ushort4 t4;
        t4.x = f2bf(acc[f][g][0]); t4.y = f2bf(acc[f][g][1]);
        t4.z = f2bf(acc[f][g][2]); t4.w = f2bf(acc[f][g][3]);
        *(ushort4*)(VT + (((size_t)(b * 8 + h) * 128 + dv) << 13) + tl) = t4;
      }
  }
}

__global__ void __launch_bounds__(512, 2)
out_gemm256(const unsigned short* __restrict__ A, const unsigned short* __restrict__ Bw,
            float* __restrict__ C) {
  extern __shared__ unsigned short lds[];
  const int tid = threadIdx.x;
  const int bx = blockIdx.x;
  const int tm = (bx & 7) * 8 + ((bx >> 3) & 7);  // 0..63
  const int tn = bx >> 6;                          // 0..3
  const int rowBase = tm * 256, colBase = tn * 256;

  f32x4 acc[8][4] = {};
  gemm256_loop(A + (size_t)rowBase * 1024, Bw + (size_t)colBase * 1024,
               lds, lds + 32768, tid, acc);

  const int lane = tid & 63, wid = tid >> 6;
  const int lq = lane & 15, quad = lane >> 4;
  const int wm = (wid >> 2) * 128, wn = (wid & 3) * 64;
#pragma unroll
  for (int f = 0; f < 8; ++f)
#pragma unroll
    for (int g = 0; g < 4; ++g) {
      const int col = colBase + wn + g * 16 + lq;
#pragma unroll
      for (int r = 0; r < 4; ++r) {
        const int row = rowBase + wm + f * 16 + quad * 4 + r;
        C[(size_t)row * 1024 + col] = acc[f][g][r];
      }
    }
}

__global__ void __launch_bounds__(256)
fm_kernel(unsigned short* __restrict__ Qb, unsigned short* __restrict__ Kb,
          const unsigned short* __restrict__ fq1b, const unsigned short* __restrict__ fq2b,
          const unsigned short* __restrict__ fk1b, const unsigned short* __restrict__ fk2b,
          const float* __restrict__ fqb1, const float* __restrict__ fqb2,
          const float* __restrict__ fkb1, const float* __restrict__ fkb2) {
  __shared__ unsigned short Aq[64 * 136];
  const int z = blockIdx.z;
  unsigned short* buf = z ? Kb : Qb;
  const unsigned short* w1b = z ? fk1b : fq1b;
  const unsigned short* w2b = z ? fk2b : fq2b;
  const float* b1 = z ? fkb1 : fqb1;
  const float* b2 = z ? fkb2 : fqb2;
  const float scale = z ? 1.0f : 0.08838834764831843f;

  const int tid = threadIdx.x;
  const int t0 = blockIdx.x * 256;
  const int h = blockIdx.y, hc = h * 128;
  const int lane = tid & 63, wid = tid >> 6, lq = lane & 15, quad = lane >> 4;
  const int wn = wid * 32;

  bf16x8 w1f[4][2], w2f[4][2];
#pragma unroll
  for (int ks = 0; ks < 4; ++ks)
#pragma unroll
    for (int j = 0; j < 2; ++j) {
      const int nr = wn + j * 16 + lq;
      w1f[ks][j] = *(const bf16x8*)(w1b + nr * 128 + ks * 32 + quad * 8);
      w2f[ks][j] = *(const bf16x8*)(w2b + nr * 128 + ks * 32 + quad * 8);
    }

  const float bb1[2] = { b1[wn + lq], b1[wn + 16 + lq] };
  const float bb2[2] = { b2[wn + lq], b2[wn + 16 + lq] };

  for (int tt = 0; tt < 4; ++tt) {
    const int tb = t0 + tt * 64;
#pragma unroll
    for (int it = 0; it < 4; ++it) {
      const int p = tid + it * 256;
      const int row = p >> 4, c8 = (p & 15) * 8;
      *(uint4*)(Aq + row * 136 + c8) =
          *(const uint4*)(buf + (size_t)(tb + row) * 1024 + hc + c8);
    }
    __syncthreads();
    f32x4 a1[4][2] = {}, a2[4][2] = {};
#pragma unroll
    for (int ks = 0; ks < 4; ++ks) {
      bf16x8 af[4];
#pragma unroll
      for (int i = 0; i < 4; ++i)
        af[i] = *(const bf16x8*)(Aq + (i * 16 + lq) * 136 + ks * 32 + quad * 8);
#pragma unroll
      for (int j = 0; j < 2; ++j)
#pragma unroll
        for (int i = 0; i < 4; ++i) {
          a1[i][j] = mfma16(af[i], w1f[ks][j], a1[i][j]);
          a2[i][j] = mfma16(af[i], w2f[ks][j], a2[i][j]);
        }
    }
    __syncthreads();
#pragma unroll
    for (int j = 0; j < 2; ++j) {
      const int col = wn + j * 16 + lq;
#pragma unroll
      for (int i = 0; i < 4; ++i)
#pragma unroll
        for (int r = 0; r < 4; ++r) {
          const float v = (a1[i][j][r] + bb1[j]) * (a2[i][j][r] + bb2[j]) * scale;
          buf[(size_t)(tb + i * 16 + quad * 4 + r) * 1024 + hc + col] = f2bf(v);
        }
    }
  }
}

__global__ void __launch_bounds__(256)
kv_kernel(const unsigned short* __restrict__ Kf, const unsigned short* __restrict__ VT,
          unsigned short* __restrict__ KV) {
  __shared__ unsigned short Kt[128 * 72];
  __shared__ unsigned short Vt[128 * 72];
  const int tid = threadIdx.x;
  const int n = blockIdx.x, bh = blockIdx.y;
  const int b = bh >> 3, h = bh & 7;
  const int t0g = b * 8192 + n * 64;
  const int tl0 = n * 64;
#pragma unroll
  for (int it = 0; it < 4; ++it) {
    const int p = tid + it * 256;
    const int d = p >> 3, c8 = (p & 7) * 8;
    *(uint4*)(Vt + d * 72 + c8) =
        *(const uint4*)(VT + (((size_t)bh * 128 + d) << 13) + tl0 + c8);
    const int tok = p >> 4, c8k = (p & 15) * 8;
    const unsigned short* src = Kf + (size_t)(t0g + tok) * 1024 + h * 128 + c8k;
    ushort4 k0 = *(const ushort4*)(src);
    ushort4 k1 = *(const ushort4*)(src + 4);
    Kt[(c8k + 0) * 72 + tok] = k0.x; Kt[(c8k + 1) * 72 + tok] = k0.y;
    Kt[(c8k + 2) * 72 + tok] = k0.z; Kt[(c8k + 3) * 72 + tok] = k0.w;
    Kt[(c8k + 4) * 72 + tok] = k1.x; Kt[(c8k + 5) * 72 + tok] = k1.y;
    Kt[(c8k + 6) * 72 + tok] = k1.z; Kt[(c8k + 7) * 72 + tok] = k1.w;
  }
  __syncthreads();
  const int lane = tid & 63, wid = tid >> 6, lq = lane & 15, quad = lane >> 4;
  const int wm = (wid >> 1) * 64, wn = (wid & 1) * 64;
  f32x4 acc[4][4] = {};
#pragma unroll
  for (int ks = 0; ks < 2; ++ks) {
    bf16x8 af[4], bfr[4];
#pragma unroll
    for (int i = 0; i < 4; ++i)
      af[i] = *(const bf16x8*)(Vt + (wm + i * 16 + lq) * 72 + ks * 32 + quad * 8);
#pragma unroll
    for (int j = 0; j < 4; ++j)
      bfr[j] = *(const bf16x8*)(Kt + (wn + j * 16 + lq) * 72 + ks * 32 + quad * 8);
#pragma unroll
    for (int i = 0; i < 4; ++i)
#pragma unroll
      for (int j = 0; j < 4; ++j) acc[i][j] = mfma16(af[i], bfr[j], acc[i][j]);
  }
  const size_t base = ((size_t)bh * 128 + n) * 16384;
#pragma unroll
  for (int i = 0; i < 4; ++i)
#pragma unroll
    for (int j = 0; j < 4; ++j)
#pragma unroll
      for (int r = 0; r < 4; ++r)
        KV[base + (size_t)(wm + i * 16 + quad * 4 + r) * 128 + wn + j * 16 + lq] =
            f2bf(acc[i][j][r]);
}

// R12: 8 loads in flight per batch (was 1 serial dependent chain of 128).
__global__ void __launch_bounds__(256)
cumsum_kernel(unsigned short* __restrict__ KV) {
  const int idx = blockIdx.x * 256 + threadIdx.x;  // 0..262143
  const int bh = idx >> 14, e = idx & 16383;
  unsigned short* p = KV + (size_t)bh * (128 * 16384) + e;
  float run = 0.f;
  for (int nb = 0; nb < 16; ++nb) {
    unsigned short x[8];
#pragma unroll
    for (int i = 0; i < 8; ++i) x[i] = p[(size_t)i * 16384];
#pragma unroll
    for (int i = 0; i < 8; ++i) {
      const float v = bf2f(x[i]);
      p[(size_t)i * 16384] = f2bf(run);  // exclusive
      run += v;
    }
    p += (size_t)8 * 16384;
  }
}

// R12: S fragments loaded global->register up front (latency hides under
// Q/K/V staging + QK^T); phases 4/6 merged; 4 fewer barriers, -64KB LDS
// traffic per block.
__global__ void __launch_bounds__(256)
attn_kernel(const unsigned short* __restrict__ Q, const unsigned short* __restrict__ Kf,
            const unsigned short* __restrict__ VT, const unsigned short* __restrict__ S,
            const float* __restrict__ rmsw, unsigned short* __restrict__ O) {
  __shared__ uint4 smem4[3968];
  unsigned short* sm = (unsigned short*)smem4;
  unsigned short* SQ = sm;            // stride 136
  unsigned short* KS = sm + 8704;     // stride 136
  unsigned short* VTl = sm + 17920;   // stride 72
  unsigned short* AL = sm + 27136;    // stride 72
  float* OL = (float*)sm;             // stride 132
  float* RED = (float*)AL;
  float* SCL = RED + 256;

  const int tid = threadIdx.x;
  const int n = blockIdx.x, bh = blockIdx.y;
  const int b = bh >> 3, h = bh & 7;
  const int t0g = b * 8192 + n * 64;
  const int tl0 = n * 64;
  const int lane = tid & 63, wid = tid >> 6, lq = lane & 15, quad = lane >> 4;

  const size_t sbase = ((size_t)bh * 128 + n) * 16384;
  // S fragments (B-operand of o += q*S): row dv = wid*32+j*16+lq,
  // col dk = hh*64 + ks*32 + quad*8 -- identical mapping to the old
  // LDS-staged sf reads (verified index algebra, phases 3-6 of R11).
  bf16x8 sfr[2][2][2];
#pragma unroll
  for (int hh = 0; hh < 2; ++hh)
#pragma unroll
    for (int ks = 0; ks < 2; ++ks)
#pragma unroll
      for (int j = 0; j < 2; ++j)
        sfr[hh][ks][j] = *(const bf16x8*)(S + sbase +
            (size_t)(wid * 32 + j * 16 + lq) * 128 + hh * 64 + ks * 32 + quad * 8);

#pragma unroll
  for (int it = 0; it < 4; ++it) {
    const int p = tid + it * 256;
    const int row = p >> 4, c8 = (p & 15) * 8;
    *(uint4*)(SQ + row * 136 + c8) =
        *(const uint4*)(Q + (size_t)(t0g + row) * 1024 + h * 128 + c8);
    *(uint4*)(KS + row * 136 + c8) =
        *(const uint4*)(Kf + (size_t)(t0g + row) * 1024 + h * 128 + c8);
    const int d = p >> 3, c8b = (p & 7) * 8;
    *(uint4*)(VTl + d * 72 + c8b) =
        *(const uint4*)(VT + (((size_t)bh * 128 + d) << 13) + tl0 + c8b);
  }
  __syncthreads();

  // A = q k^T, mask, -> AL
  {
    f32x4 aa[4] = {};
#pragma unroll
    for (int ks = 0; ks < 4; ++ks) {
      bf16x8 kf = *(const bf16x8*)(KS + (wid * 16 + lq) * 136 + ks * 32 + quad * 8);
#pragma unroll
      for (int i = 0; i < 4; ++i) {
        bf16x8 qf = *(const bf16x8*)(SQ + (i * 16 + lq) * 136 + ks * 32 + quad * 8);
        aa[i] = mfma16(qf, kf, aa[i]);
      }
    }
#pragma unroll
    for (int i = 0; i < 4; ++i)
#pragma unroll
      for (int r = 0; r < 4; ++r) {
        const int qp = i * 16 + quad * 4 + r, kp = wid * 16 + lq;
        AL[qp * 72 + kp] = f2bf(kp <= qp ? aa[i][r] : 0.f);
      }
  }
  __syncthreads();

  // o = A_masked * V + q * S (both S halves via sfr)
  f32x4 oa[4][2] = {};
#pragma unroll
  for (int ks = 0; ks < 2; ++ks) {
    bf16x8 bv[2];
#pragma unroll
    for (int j = 0; j < 2; ++j)
      bv[j] = *(const bf16x8*)(VTl + (wid * 32 + j * 16 + lq) * 72 + ks * 32 + quad * 8);
#pragma unroll
    for (int i = 0; i < 4; ++i) {
      bf16x8 af  = *(const bf16x8*)(AL + (i * 16 + lq) * 72 + ks * 32 + quad * 8);
      bf16x8 qf0 = *(const bf16x8*)(SQ + (i * 16 + lq) * 136 + ks * 32 + quad * 8);
      bf16x8 qf1 = *(const bf16x8*)(SQ + (i * 16 + lq) * 136 + (ks + 2) * 32 + quad * 8);
#pragma unroll
      for (int j = 0; j < 2; ++j) {
        oa[i][j] = mfma16(af, bv[j], oa[i][j]);
        oa[i][j] = mfma16(qf0, sfr[0][ks][j], oa[i][j]);
        oa[i][j] = mfma16(qf1, sfr[1][ks][j], oa[i][j]);
      }
    }
  }
  __syncthreads();

  // spill o (fp32) to LDS for cross-wave RMSNorm
#pragma unroll
  for (int i = 0; i < 4; ++i)
#pragma unroll
    for (int j = 0; j < 2; ++j)
#pragma unroll
      for (int r = 0; r < 4; ++r)
        OL[(i * 16 + quad * 4 + r) * 132 + wid * 32 + j * 16 + lq] = oa[i][j][r];
  __syncthreads();

  {
    const int r = tid >> 2, part = tid & 3;
    const float* pr = OL + r * 132 + part * 32;
    float s = 0.f;
#pragma unroll
    for (int c = 0; c < 32; ++c) { const float v = pr[c]; s += v * v; }
    RED[r * 4 + part] = s;
  }
  __syncthreads();
  if (tid < 64) {
    const float ms = (RED[tid * 4] + RED[tid * 4 + 1] + RED[tid * 4 + 2] + RED[tid * 4 + 3]) *
                     (1.f / 128.f);
    SCL[tid] = rsqrtf(ms + 1e-5f);
  }
  __syncthreads();

#pragma unroll
  for (int it = 0; it < 4; ++it) {
    const int r = (tid >> 4) + it * 16;
    const int c8 = (tid & 15) * 8;
    const float sc = SCL[r];
    unsigned short us[8];
#pragma unroll
    for (int e = 0; e < 8; ++e)
      us[e] = f2bf(OL[r * 132 + c8 + e] * sc * rmsw[c8 + e]);
    uint4 pk;
    pk.x = (unsigned int)us[0] | ((unsigned int)us[1] << 16);
    pk.y = (unsigned int)us[2] | ((unsigned int)us[3] << 16);
    pk.z = (unsigned int)us[4] | ((unsigned int)us[5] << 16);
    pk.w = (unsigned int)us[6] | ((unsigned int)us[7] << 16);
    *(uint4*)(O + (size_t)(t0g + r) * 1024 + h * 128 + c8) = pk;
  }
}

extern "C" void kernel_launch(void* const* d_in, const int* in_sizes, int n_in,
                              void* d_out, int out_size, void* d_ws, size_t ws_size,
                              hipStream_t stream) {
  const float* X    = (const float*)d_in[0];
  const float* Wq   = (const float*)d_in[1];
  const float* Wk   = (const float*)d_in[2];
  const float* Wv   = (const float*)d_in[3];
  const float* fq1  = (const float*)d_in[4];
  const float* fqb1 = (const float*)d_in[5];
  const float* fq2  = (const float*)d_in[6];
  const float* fqb2 = (const float*)d_in[7];
  const float* fk1  = (const float*)d_in[8];
  const float* fkb1 = (const float*)d_in[9];
  const float* fk2  = (const float*)d_in[10];
  const float* fkb2 = (const float*)d_in[11];
  const float* rmsw = (const float*)d_in[12];
  const float* Wo   = (const float*)d_in[13];

  static bool attr_done = false;
  if (!attr_done) {
    (void)hipFuncSetAttribute((const void*)qkv_gemm256,
                              hipFuncAttributeMaxDynamicSharedMemorySize, 131072);
    (void)hipFuncSetAttribute((const void*)out_gemm256,
                              hipFuncAttributeMaxDynamicSharedMemorySize, 131072);
    attr_done = true;
  }

  const size_t MB = 1u << 20;
  char* ws = (char*)d_ws;
  unsigned short* Q    = (unsigned short*)(ws);
  unsigned short* Kf   = (unsigned short*)(ws + 32 * MB);
  unsigned short* VT   = (unsigned short*)(ws + 64 * MB);
  unsigned short* KV   = (unsigned short*)(ws + 96 * MB);
  unsigned short* Xb   = KV;
  unsigned short* Wqb  = (unsigned short*)(ws + 160 * MB);
  unsigned short* Wkb  = (unsigned short*)(ws + 162 * MB);
  unsigned short* Wvb  = (unsigned short*)(ws + 164 * MB);
  unsigned short* Wob  = (unsigned short*)(ws + 166 * MB);
  unsigned short* fq1b = (unsigned short*)(ws + 168 * MB);
  unsigned short* fq2b = fq1b + 16384;
  unsigned short* fk1b = fq1b + 32768;
  unsigned short* fk2b = fq1b + 49152;
  unsigned short* O    = Q;

  cvt4_kernel<<<dim3(1024, 4), 256, 0, stream>>>(Wq, Wk, Wv, Wo,
                                                 Wqb, Wkb, Wvb, Wob, 262144);
  cvt4_kernel<<<dim3(16, 4), 256, 0, stream>>>(fq1, fq2, fk1, fk2,
                                               fq1b, fq2b, fk1b, fk2b, 4096);
  cvt_kernel<<<16384, 256, 0, stream>>>(X, Xb, 4194304);

  qkv_gemm256<<<dim3(768), dim3(512), 131072, stream>>>(Xb, Wqb, Wkb, Wvb, Q, Kf, VT);
  fm_kernel<<<dim3(64, 8, 2), 256, 0, stream>>>(Q, Kf, fq1b, fq2b, fk1b, fk2b,
                                                fqb1, fqb2, fkb1, fkb2);
  kv_kernel<<<dim3(128, 16), 256, 0, stream>>>(Kf, VT, KV);
  cumsum_kernel<<<1024, 256, 0, stream>>>(KV);
  attn_kernel<<<dim3(128, 16), 256, 0, stream>>>(Q, Kf, VT, KV, rmsw, O);
  out_gemm256<<<dim3(256), dim3(512), 131072, stream>>>(O, Wob, (float*)d_out);
}

// Round 8
// 394.696 us; speedup vs baseline: 1.0364x; 1.0364x over previous
//
#include <hip/hip_runtime.h>

// LinearAttention forward. B=2, T=8192 (BT=16384), HID=1024, H=8, DK=DV=128.
// ws (MB): [0,32) Q/O | [32,64) Kf | [64,96) VT | [96,160) KV (Xb overlays) |
//   [160,168) W bf16 | [168,+128KB) fm weights bf16
// R13: visibility round. qkv split into 3 launches (sel arg) so non-GEMM
//   kernels surface in rocprof top-5; all cvts fused into one launch.
//   GEMM core = R10 (100.5us, 44.5% MfmaUtil; 2-blk/CU impossible: acc=128
//   AGPR/wave caps 8 waves/CU). attn/fm/kv/cumsum unchanged from R12.

typedef __bf16 bf16x8 __attribute__((ext_vector_type(8)));
typedef float  f32x4  __attribute__((ext_vector_type(4)));

__device__ __forceinline__ float bf2f(unsigned short u) {
  union { unsigned int i; float f; } v; v.i = ((unsigned int)u) << 16; return v.f;
}
__device__ __forceinline__ unsigned short f2bf(float f) {
  union { float f; unsigned int i; } v; v.f = f;
  return (unsigned short)((v.i + 0x8000u) >> 16);
}
__device__ __forceinline__ unsigned int pk2(float a, float b) {
  union { float f; unsigned int i; } x, y; x.f = a; y.f = b;
  return ((x.i + 0x8000u) >> 16) | ((y.i + 0x8000u) & 0xFFFF0000u);
}
__device__ __forceinline__ f32x4 mfma16(bf16x8 a, bf16x8 b, f32x4 c) {
  return __builtin_amdgcn_mfma_f32_16x16x32_bf16(a, b, c, 0, 0, 0);
}
__device__ __forceinline__ void gl_lds16(const unsigned short* g, unsigned short* l) {
  __builtin_amdgcn_global_load_lds((const __attribute__((address_space(1))) void*)g,
                                   (__attribute__((address_space(3))) void*)l, 16, 0, 0);
}

// R13: all f32->bf16 conversions in ONE launch. 1D grid over float4 units:
// [0, 4194304) X | [+0, 1048576) Wq/Wk/Wv/Wo (262144 each) |
// [+0, 16384) fq1/fq2/fk1/fk2 (4096 each). Total 5259264 -> 20544 blocks.
__global__ void __launch_bounds__(256)
cvt_all(const float* __restrict__ X,
        const float* __restrict__ W0, const float* __restrict__ W1,
        const float* __restrict__ W2, const float* __restrict__ W3,
        const float* __restrict__ F0, const float* __restrict__ F1,
        const float* __restrict__ F2, const float* __restrict__ F3,
        unsigned short* __restrict__ Xd,
        unsigned short* __restrict__ W0d, unsigned short* __restrict__ W1d,
        unsigned short* __restrict__ W2d, unsigned short* __restrict__ W3d,
        unsigned short* __restrict__ F0d, unsigned short* __restrict__ F1d,
        unsigned short* __restrict__ F2d, unsigned short* __restrict__ F3d) {
  const int i = blockIdx.x * 256 + threadIdx.x;
  const float* s; unsigned short* d; int off;
  if (i < 4194304) { s = X; d = Xd; off = i; }
  else {
    int i2 = i - 4194304;
    if (i2 < 1048576) {
      const int w = i2 >> 18; off = i2 & 262143;
      s = (w == 0) ? W0 : (w == 1) ? W1 : (w == 2) ? W2 : W3;
      d = (w == 0) ? W0d : (w == 1) ? W1d : (w == 2) ? W2d : W3d;
    } else {
      int i3 = i2 - 1048576;
      if (i3 >= 16384) return;
      const int w = i3 >> 12; off = i3 & 4095;
      s = (w == 0) ? F0 : (w == 1) ? F1 : (w == 2) ? F2 : F3;
      d = (w == 0) ? F0d : (w == 1) ? F1d : (w == 2) ? F2d : F3d;
    }
  }
  const float4 f = ((const float4*)s)[off];
  uint2 o; o.x = pk2(f.x, f.y); o.y = pk2(f.z, f.w);
  ((uint2*)d)[off] = o;
}

// slot s of a swizzled 256x32 unit: j=s>>3, c=(s&7)^(j&7), row=2j+(c>>2),
// k-chunk c&3. Returns element offset in global [256,1024] source.
__device__ __forceinline__ int stage_goff(int s) {
  const int j = s >> 3, c = (s & 7) ^ (j & 7);
  return (2 * j + (c >> 2)) * 1024 + (c & 3) * 8;
}

// R10 core: 4-deep LDS ring, one barrier per 32-K step, register-prefetch one
// subtile ahead so ds_reads of step u+1 drain during the 32-MFMA cluster of u.
__device__ __forceinline__ void gemm256_loop(const unsigned short* __restrict__ gA,
                                             const unsigned short* __restrict__ gB,
                                             unsigned short* __restrict__ ldsA,
                                             unsigned short* __restrict__ ldsB,
                                             int tid, f32x4 (&acc)[8][4]) {
  const int lane = tid & 63, wid = tid >> 6;
  const int lq = lane & 15, quad = lane >> 4;
  const int wm = (wid >> 2) * 128, wn = (wid & 3) * 64;

  const unsigned short* gA0 = gA + stage_goff(tid);
  const unsigned short* gA1 = gA + stage_goff(512 + tid);
  const unsigned short* gB0 = gB + stage_goff(tid);
  const unsigned short* gB1 = gB + stage_goff(512 + tid);
  const int l0 = wid * 512;
  const int l1 = 4096 + wid * 512;
  const int soff = (lq >> 1) * 64 + (((((lq & 1) << 2) + quad) ^ ((lq >> 1) & 7))) * 8;

#pragma unroll
  for (int h = 0; h < 3; ++h) {
    gl_lds16(gA0 + h * 32, ldsA + h * 8192 + l0);
    gl_lds16(gA1 + h * 32, ldsA + h * 8192 + l1);
    gl_lds16(gB0 + h * 32, ldsB + h * 8192 + l0);
    gl_lds16(gB1 + h * 32, ldsB + h * 8192 + l1);
  }
  asm volatile("s_waitcnt vmcnt(4)" ::: "memory");
  __builtin_amdgcn_s_barrier();
  __builtin_amdgcn_sched_barrier(0);

  bf16x8 pa[2][8], pb[2][4];
#pragma unroll
  for (int f = 0; f < 8; ++f)
    pa[0][f] = *(const bf16x8*)(ldsA + (wm + f * 16) * 32 + soff);
#pragma unroll
  for (int g = 0; g < 4; ++g)
    pb[0][g] = *(const bf16x8*)(ldsB + (wn + g * 16) * 32 + soff);

#pragma unroll
  for (int u = 0; u < 32; ++u) {
    const int cur = u & 1, nxt = cur ^ 1;
    if (u > 0) {
      if (u < 30) asm volatile("s_waitcnt vmcnt(4)" ::: "memory");
      else        asm volatile("s_waitcnt vmcnt(0)" ::: "memory");
      __builtin_amdgcn_s_barrier();
      __builtin_amdgcn_sched_barrier(0);
    }
    if (u < 29) {
      unsigned short* sa = ldsA + ((u + 3) & 3) * 8192;
      unsigned short* sb = ldsB + ((u + 3) & 3) * 8192;
      gl_lds16(gA0 + (u + 3) * 32, sa + l0);
      gl_lds16(gA1 + (u + 3) * 32, sa + l1);
      gl_lds16(gB0 + (u + 3) * 32, sb + l0);
      gl_lds16(gB1 + (u + 3) * 32, sb + l1);
    }
    if (u < 31) {
      const unsigned short* An = ldsA + ((u + 1) & 3) * 8192;
      const unsigned short* Bn = ldsB + ((u + 1) & 3) * 8192;
#pragma unroll
      for (int f = 0; f < 8; ++f)
        pa[nxt][f] = *(const bf16x8*)(An + (wm + f * 16) * 32 + soff);
#pragma unroll
      for (int g = 0; g < 4; ++g)
        pb[nxt][g] = *(const bf16x8*)(Bn + (wn + g * 16) * 32 + soff);
    }
    __builtin_amdgcn_s_setprio(1);
#pragma unroll
    for (int f = 0; f < 8; ++f)
#pragma unroll
      for (int g = 0; g < 4; ++g)
        acc[f][g] = mfma16(pa[cur][f], pb[cur][g], acc[f][g]);
    __builtin_amdgcn_s_setprio(0);
  }
}

// R13: one sel per launch (256 blocks). tm=(bx&7)*8+((bx>>3)&7), ct=bx>>6.
__global__ void __launch_bounds__(512, 2)
qkv_gemm256(const unsigned short* __restrict__ Xb, const unsigned short* __restrict__ Bw,
            unsigned short* __restrict__ Cq, unsigned short* __restrict__ VT, int sel) {
  extern __shared__ unsigned short lds[];
  const int tid = threadIdx.x;
  const int bx = blockIdx.x;
  const int tm = (bx & 7) * 8 + ((bx >> 3) & 7);  // 0..63
  const int ct = bx >> 6;                          // 0..3
  const int rowBase = tm * 256, colBase = ct * 256;

  f32x4 acc[8][4] = {};
  gemm256_loop(Xb + (size_t)rowBase * 1024, Bw + (size_t)colBase * 1024,
               lds, lds + 32768, tid, acc);

  const int lane = tid & 63, wid = tid >> 6;
  const int lq = lane & 15, quad = lane >> 4;
  const int wm = (wid >> 2) * 128, wn = (wid & 3) * 64;
  if (sel < 2) {
#pragma unroll
    for (int f = 0; f < 8; ++f)
#pragma unroll
      for (int g = 0; g < 4; ++g) {
        const int col = colBase + wn + g * 16 + lq;
#pragma unroll
        for (int r = 0; r < 4; ++r) {
          const int row = rowBase + wm + f * 16 + quad * 4 + r;
          Cq[(size_t)row * 1024 + col] = f2bf(acc[f][g][r]);
        }
      }
  } else {
#pragma unroll
    for (int f = 0; f < 8; ++f)
#pragma unroll
      for (int g = 0; g < 4; ++g) {
        const int col = colBase + wn + g * 16 + lq;
        const int h = col >> 7, dv = col & 127;
        const int row0 = rowBase + wm + f * 16 + quad * 4;
        const int b = row0 >> 13, tl = row0 & 8191;
        ushort4 t4;
        t4.x = f2bf(acc[f][g][0]); t4.y = f2bf(acc[f][g][1]);
        t4.z = f2bf(acc[f][g][2]); t4.w = f2bf(acc[f][g][3]);
        *(ushort4*)(VT + (((size_t)(b * 8 + h) * 128 + dv) << 13) + tl) = t4;
      }
  }
}

__global__ void __launch_bounds__(512, 2)
out_gemm256(const unsigned short* __restrict__ A, const unsigned short* __restrict__ Bw,
            float* __restrict__ C) {
  extern __shared__ unsigned short lds[];
  const int tid = threadIdx.x;
  const int bx = blockIdx.x;
  const int tm = (bx & 7) * 8 + ((bx >> 3) & 7);  // 0..63
  const int tn = bx >> 6;                          // 0..3
  const int rowBase = tm * 256, colBase = tn * 256;

  f32x4 acc[8][4] = {};
  gemm256_loop(A + (size_t)rowBase * 1024, Bw + (size_t)colBase * 1024,
               lds, lds + 32768, tid, acc);

  const int lane = tid & 63, wid = tid >> 6;
  const int lq = lane & 15, quad = lane >> 4;
  const int wm = (wid >> 2) * 128, wn = (wid & 3) * 64;
#pragma unroll
  for (int f = 0; f < 8; ++f)
#pragma unroll
    for (int g = 0; g < 4; ++g) {
      const int col = colBase + wn + g * 16 + lq;
#pragma unroll
      for (int r = 0; r < 4; ++r) {
        const int row = rowBase + wm + f * 16 + quad * 4 + r;
        C[(size_t)row * 1024 + col] = acc[f][g][r];
      }
    }
}

__global__ void __launch_bounds__(256)
fm_kernel(unsigned short* __restrict__ Qb, unsigned short* __restrict__ Kb,
          const unsigned short* __restrict__ fq1b, const unsigned short* __restrict__ fq2b,
          const unsigned short* __restrict__ fk1b, const unsigned short* __restrict__ fk2b,
          const float* __restrict__ fqb1, const float* __restrict__ fqb2,
          const float* __restrict__ fkb1, const float* __restrict__ fkb2) {
  __shared__ unsigned short Aq[64 * 136];
  const int z = blockIdx.z;
  unsigned short* buf = z ? Kb : Qb;
  const unsigned short* w1b = z ? fk1b : fq1b;
  const unsigned short* w2b = z ? fk2b : fq2b;
  const float* b1 = z ? fkb1 : fqb1;
  const float* b2 = z ? fkb2 : fqb2;
  const float scale = z ? 1.0f : 0.08838834764831843f;

  const int tid = threadIdx.x;
  const int t0 = blockIdx.x * 256;
  const int h = blockIdx.y, hc = h * 128;
  const int lane = tid & 63, wid = tid >> 6, lq = lane & 15, quad = lane >> 4;
  const int wn = wid * 32;

  bf16x8 w1f[4][2], w2f[4][2];
#pragma unroll
  for (int ks = 0; ks < 4; ++ks)
#pragma unroll
    for (int j = 0; j < 2; ++j) {
      const int nr = wn + j * 16 + lq;
      w1f[ks][j] = *(const bf16x8*)(w1b + nr * 128 + ks * 32 + quad * 8);
      w2f[ks][j] = *(const bf16x8*)(w2b + nr * 128 + ks * 32 + quad * 8);
    }

  const float bb1[2] = { b1[wn + lq], b1[wn + 16 + lq] };
  const float bb2[2] = { b2[wn + lq], b2[wn + 16 + lq] };

  for (int tt = 0; tt < 4; ++tt) {
    const int tb = t0 + tt * 64;
#pragma unroll
    for (int it = 0; it < 4; ++it) {
      const int p = tid + it * 256;
      const int row = p >> 4, c8 = (p & 15) * 8;
      *(uint4*)(Aq + row * 136 + c8) =
          *(const uint4*)(buf + (size_t)(tb + row) * 1024 + hc + c8);
    }
    __syncthreads();
    f32x4 a1[4][2] = {}, a2[4][2] = {};
#pragma unroll
    for (int ks = 0; ks < 4; ++ks) {
      bf16x8 af[4];
#pragma unroll
      for (int i = 0; i < 4; ++i)
        af[i] = *(const bf16x8*)(Aq + (i * 16 + lq) * 136 + ks * 32 + quad * 8);
#pragma unroll
      for (int j = 0; j < 2; ++j)
#pragma unroll
        for (int i = 0; i < 4; ++i) {
          a1[i][j] = mfma16(af[i], w1f[ks][j], a1[i][j]);
          a2[i][j] = mfma16(af[i], w2f[ks][j], a2[i][j]);
        }
    }
    __syncthreads();
#pragma unroll
    for (int j = 0; j < 2; ++j) {
      const int col = wn + j * 16 + lq;
#pragma unroll
      for (int i = 0; i < 4; ++i)
#pragma unroll
        for (int r = 0; r < 4; ++r) {
          const float v = (a1[i][j][r] + bb1[j]) * (a2[i][j][r] + bb2[j]) * scale;
          buf[(size_t)(tb + i * 16 + quad * 4 + r) * 1024 + hc + col] = f2bf(v);
        }
    }
  }
}

__global__ void __launch_bounds__(256)
kv_kernel(const unsigned short* __restrict__ Kf, const unsigned short* __restrict__ VT,
          unsigned short* __restrict__ KV) {
  __shared__ unsigned short Kt[128 * 72];
  __shared__ unsigned short Vt[128 * 72];
  const int tid = threadIdx.x;
  const int n = blockIdx.x, bh = blockIdx.y;
  const int b = bh >> 3, h = bh & 7;
  const int t0g = b * 8192 + n * 64;
  const int tl0 = n * 64;
#pragma unroll
  for (int it = 0; it < 4; ++it) {
    const int p = tid + it * 256;
    const int d = p >> 3, c8 = (p & 7) * 8;
    *(uint4*)(Vt + d * 72 + c8) =
        *(const uint4*)(VT + (((size_t)bh * 128 + d) << 13) + tl0 + c8);
    const int tok = p >> 4, c8k = (p & 15) * 8;
    const unsigned short* src = Kf + (size_t)(t0g + tok) * 1024 + h * 128 + c8k;
    ushort4 k0 = *(const ushort4*)(src);
    ushort4 k1 = *(const ushort4*)(src + 4);
    Kt[(c8k + 0) * 72 + tok] = k0.x; Kt[(c8k + 1) * 72 + tok] = k0.y;
    Kt[(c8k + 2) * 72 + tok] = k0.z; Kt[(c8k + 3) * 72 + tok] = k0.w;
    Kt[(c8k + 4) * 72 + tok] = k1.x; Kt[(c8k + 5) * 72 + tok] = k1.y;
    Kt[(c8k + 6) * 72 + tok] = k1.z; Kt[(c8k + 7) * 72 + tok] = k1.w;
  }
  __syncthreads();
  const int lane = tid & 63, wid = tid >> 6, lq = lane & 15, quad = lane >> 4;
  const int wm = (wid >> 1) * 64, wn = (wid & 1) * 64;
  f32x4 acc[4][4] = {};
#pragma unroll
  for (int ks = 0; ks < 2; ++ks) {
    bf16x8 af[4], bfr[4];
#pragma unroll
    for (int i = 0; i < 4; ++i)
      af[i] = *(const bf16x8*)(Vt + (wm + i * 16 + lq) * 72 + ks * 32 + quad * 8);
#pragma unroll
    for (int j = 0; j < 4; ++j)
      bfr[j] = *(const bf16x8*)(Kt + (wn + j * 16 + lq) * 72 + ks * 32 + quad * 8);
#pragma unroll
    for (int i = 0; i < 4; ++i)
#pragma unroll
      for (int j = 0; j < 4; ++j) acc[i][j] = mfma16(af[i], bfr[j], acc[i][j]);
  }
  const size_t base = ((size_t)bh * 128 + n) * 16384;
#pragma unroll
  for (int i = 0; i < 4; ++i)
#pragma unroll
    for (int j = 0; j < 4; ++j)
#pragma unroll
      for (int r = 0; r < 4; ++r)
        KV[base + (size_t)(wm + i * 16 + quad * 4 + r) * 128 + wn + j * 16 + lq] =
            f2bf(acc[i][j][r]);
}

__global__ void __launch_bounds__(256)
cumsum_kernel(unsigned short* __restrict__ KV) {
  const int idx = blockIdx.x * 256 + threadIdx.x;  // 0..262143
  const int bh = idx >> 14, e = idx & 16383;
  unsigned short* p = KV + (size_t)bh * (128 * 16384) + e;
  float run = 0.f;
  for (int nb = 0; nb < 16; ++nb) {
    unsigned short x[8];
#pragma unroll
    for (int i = 0; i < 8; ++i) x[i] = p[(size_t)i * 16384];
#pragma unroll
    for (int i = 0; i < 8; ++i) {
      const float v = bf2f(x[i]);
      p[(size_t)i * 16384] = f2bf(run);  // exclusive
      run += v;
    }
    p += (size_t)8 * 16384;
  }
}

__global__ void __launch_bounds__(256)
attn_kernel(const unsigned short* __restrict__ Q, const unsigned short* __restrict__ Kf,
            const unsigned short* __restrict__ VT, const unsigned short* __restrict__ S,
            const float* __restrict__ rmsw, unsigned short* __restrict__ O) {
  __shared__ uint4 smem4[3968];
  unsigned short* sm = (unsigned short*)smem4;
  unsigned short* SQ = sm;            // stride 136
  unsigned short* KS = sm + 8704;     // stride 136
  unsigned short* VTl = sm + 17920;   // stride 72
  unsigned short* AL = sm + 27136;    // stride 72
  float* OL = (float*)sm;             // stride 132
  float* RED = (float*)AL;
  float* SCL = RED + 256;

  const int tid = threadIdx.x;
  const int n = blockIdx.x, bh = blockIdx.y;
  const int b = bh >> 3, h = bh & 7;
  const int t0g = b * 8192 + n * 64;
  const int tl0 = n * 64;
  const int lane = tid & 63, wid = tid >> 6, lq = lane & 15, quad = lane >> 4;

  const size_t sbase = ((size_t)bh * 128 + n) * 16384;
  bf16x8 sfr[2][2][2];
#pragma unroll
  for (int hh = 0; hh < 2; ++hh)
#pragma unroll
    for (int ks = 0; ks < 2; ++ks)
#pragma unroll
      for (int j = 0; j < 2; ++j)
        sfr[hh][ks][j] = *(const bf16x8*)(S + sbase +
            (size_t)(wid * 32 + j * 16 + lq) * 128 + hh * 64 + ks * 32 + quad * 8);

#pragma unroll
  for (int it = 0; it < 4; ++it) {
    const int p = tid + it * 256;
    const int row = p >> 4, c8 = (p & 15) * 8;
    *(uint4*)(SQ + row * 136 + c8) =
        *(const uint4*)(Q + (size_t)(t0g + row) * 1024 + h * 128 + c8);
    *(uint4*)(KS + row * 136 + c8) =
        *(const uint4*)(Kf + (size_t)(t0g + row) * 1024 + h * 128 + c8);
    const int d = p >> 3, c8b = (p & 7) * 8;
    *(uint4*)(VTl + d * 72 + c8b) =
        *(const uint4*)(VT + (((size_t)bh * 128 + d) << 13) + tl0 + c8b);
  }
  __syncthreads();

  {
    f32x4 aa[4] = {};
#pragma unroll
    for (int ks = 0; ks < 4; ++ks) {
      bf16x8 kf = *(const bf16x8*)(KS + (wid * 16 + lq) * 136 + ks * 32 + quad * 8);
#pragma unroll
      for (int i = 0; i < 4; ++i) {
        bf16x8 qf = *(const bf16x8*)(SQ + (i * 16 + lq) * 136 + ks * 32 + quad * 8);
        aa[i] = mfma16(qf, kf, aa[i]);
      }
    }
#pragma unroll
    for (int i = 0; i < 4; ++i)
#pragma unroll
      for (int r = 0; r < 4; ++r) {
        const int qp = i * 16 + quad * 4 + r, kp = wid * 16 + lq;
        AL[qp * 72 + kp] = f2bf(kp <= qp ? aa[i][r] : 0.f);
      }
  }
  __syncthreads();

  f32x4 oa[4][2] = {};
#pragma unroll
  for (int ks = 0; ks < 2; ++ks) {
    bf16x8 bv[2];
#pragma unroll
    for (int j = 0; j < 2; ++j)
      bv[j] = *(const bf16x8*)(VTl + (wid * 32 + j * 16 + lq) * 72 + ks * 32 + quad * 8);
#pragma unroll
    for (int i = 0; i < 4; ++i) {
      bf16x8 af  = *(const bf16x8*)(AL + (i * 16 + lq) * 72 + ks * 32 + quad * 8);
      bf16x8 qf0 = *(const bf16x8*)(SQ + (i * 16 + lq) * 136 + ks * 32 + quad * 8);
      bf16x8 qf1 = *(const bf16x8*)(SQ + (i * 16 + lq) * 136 + (ks + 2) * 32 + quad * 8);
#pragma unroll
      for (int j = 0; j < 2; ++j) {
        oa[i][j] = mfma16(af, bv[j], oa[i][j]);
        oa[i][j] = mfma16(qf0, sfr[0][ks][j], oa[i][j]);
        oa[i][j] = mfma16(qf1, sfr[1][ks][j], oa[i][j]);
      }
    }
  }
  __syncthreads();

#pragma unroll
  for (int i = 0; i < 4; ++i)
#pragma unroll
    for (int j = 0; j < 2; ++j)
#pragma unroll
      for (int r = 0; r < 4; ++r)
        OL[(i * 16 + quad * 4 + r) * 132 + wid * 32 + j * 16 + lq] = oa[i][j][r];
  __syncthreads();

  {
    const int r = tid >> 2, part = tid & 3;
    const float* pr = OL + r * 132 + part * 32;
    float s = 0.f;
#pragma unroll
    for (int c = 0; c < 32; ++c) { const float v = pr[c]; s += v * v; }
    RED[r * 4 + part] = s;
  }
  __syncthreads();
  if (tid < 64) {
    const float ms = (RED[tid * 4] + RED[tid * 4 + 1] + RED[tid * 4 + 2] + RED[tid * 4 + 3]) *
                     (1.f / 128.f);
    SCL[tid] = rsqrtf(ms + 1e-5f);
  }
  __syncthreads();

#pragma unroll
  for (int it = 0; it < 4; ++it) {
    const int r = (tid >> 4) + it * 16;
    const int c8 = (tid & 15) * 8;
    const float sc = SCL[r];
    unsigned short us[8];
#pragma unroll
    for (int e = 0; e < 8; ++e)
      us[e] = f2bf(OL[r * 132 + c8 + e] * sc * rmsw[c8 + e]);
    uint4 pk;
    pk.x = (unsigned int)us[0] | ((unsigned int)us[1] << 16);
    pk.y = (unsigned int)us[2] | ((unsigned int)us[3] << 16);
    pk.z = (unsigned int)us[4] | ((unsigned int)us[5] << 16);
    pk.w = (unsigned int)us[6] | ((unsigned int)us[7] << 16);
    *(uint4*)(O + (size_t)(t0g + r) * 1024 + h * 128 + c8) = pk;
  }
}

extern "C" void kernel_launch(void* const* d_in, const int* in_sizes, int n_in,
                              void* d_out, int out_size, void* d_ws, size_t ws_size,
                              hipStream_t stream) {
  const float* X    = (const float*)d_in[0];
  const float* Wq   = (const float*)d_in[1];
  const float* Wk   = (const float*)d_in[2];
  const float* Wv   = (const float*)d_in[3];
  const float* fq1  = (const float*)d_in[4];
  const float* fqb1 = (const float*)d_in[5];
  const float* fq2  = (const float*)d_in[6];
  const float* fqb2 = (const float*)d_in[7];
  const float* fk1  = (const float*)d_in[8];
  const float* fkb1 = (const float*)d_in[9];
  const float* fk2  = (const float*)d_in[10];
  const float* fkb2 = (const float*)d_in[11];
  const float* rmsw = (const float*)d_in[12];
  const float* Wo   = (const float*)d_in[13];

  static bool attr_done = false;
  if (!attr_done) {
    (void)hipFuncSetAttribute((const void*)qkv_gemm256,
                              hipFuncAttributeMaxDynamicSharedMemorySize, 131072);
    (void)hipFuncSetAttribute((const void*)out_gemm256,
                              hipFuncAttributeMaxDynamicSharedMemorySize, 131072);
    attr_done = true;
  }

  const size_t MB = 1u << 20;
  char* ws = (char*)d_ws;
  unsigned short* Q    = (unsigned short*)(ws);
  unsigned short* Kf   = (unsigned short*)(ws + 32 * MB);
  unsigned short* VT   = (unsigned short*)(ws + 64 * MB);
  unsigned short* KV   = (unsigned short*)(ws + 96 * MB);
  unsigned short* Xb   = KV;
  unsigned short* Wqb  = (unsigned short*)(ws + 160 * MB);
  unsigned short* Wkb  = (unsigned short*)(ws + 162 * MB);
  unsigned short* Wvb  = (unsigned short*)(ws + 164 * MB);
  unsigned short* Wob  = (unsigned short*)(ws + 166 * MB);
  unsigned short* fq1b = (unsigned short*)(ws + 168 * MB);
  unsigned short* fq2b = fq1b + 16384;
  unsigned short* fk1b = fq1b + 32768;
  unsigned short* fk2b = fq1b + 49152;
  unsigned short* O    = Q;

  cvt_all<<<20544, 256, 0, stream>>>(X, Wq, Wk, Wv, Wo, fq1, fq2, fk1, fk2,
                                     Xb, Wqb, Wkb, Wvb, Wob,
                                     fq1b, fq2b, fk1b, fk2b);

  qkv_gemm256<<<dim3(256), dim3(512), 131072, stream>>>(Xb, Wqb, Q, VT, 0);
  qkv_gemm256<<<dim3(256), dim3(512), 131072, stream>>>(Xb, Wkb, Kf, VT, 1);
  qkv_gemm256<<<dim3(256), dim3(512), 131072, stream>>>(Xb, Wvb, Q, VT, 2);
  fm_kernel<<<dim3(64, 8, 2), 256, 0, stream>>>(Q, Kf, fq1b, fq2b, fk1b, fk2b,
                                                fqb1, fqb2, fkb1, fkb2);
  kv_kernel<<<dim3(128, 16), 256, 0, stream>>>(Kf, VT, KV);
  cumsum_kernel<<<1024, 256, 0, stream>>>(KV);
  attn_kernel<<<dim3(128, 16), 256, 0, stream>>>(Q, Kf, VT, KV, rmsw, O);
  out_gemm256<<<dim3(256), dim3(512), 131072, stream>>>(O, Wob, (float*)d_out);
}